// Round 17
// baseline (267.871 us; speedup 1.0000x reference)
//
#include <hip/hip_runtime.h>

typedef float  f32x4  __attribute__((ext_vector_type(4)));
typedef int    i32x4  __attribute__((ext_vector_type(4)));
typedef __bf16 bf16x8 __attribute__((ext_vector_type(8)));

#define MFMA_BF16(a, b, c) __builtin_amdgcn_mfma_f32_16x16x32_bf16((a), (b), (c), 0, 0, 0)

// ---------- constants ----------
#define BDIM   4
#define SEQ    2048
#define DM     512
#define NH     8
#define DK     64
#define KT     64           // k-tile
#define NT     (SEQ / KT)   // 32
#define QB     128          // q-rows per block (4 waves x 2 subtiles x 16)
#define PS     72           // P-tile LDS stride (shorts)
#define KTDK   (KT * DK)    // shorts per K tile
// softmax in exp2 domain: exp(s*0.125) = exp2(s * 0.125*log2(e))
#define C2LOG2E  0.18033688011112042f
#define MASKED_X (-115.41560327111707f)   // -80 * log2(e); exp2 -> 2.37e-35 (normal)

static __device__ __forceinline__ unsigned short f2bf(float f) {
  unsigned int u = __builtin_bit_cast(unsigned int, f);
  u += 0x7fffu + ((u >> 16) & 1u);   // round-to-nearest-even
  return (unsigned short)(u >> 16);
}
static __device__ __forceinline__ unsigned short rhu(float f) {   // round-half-up, 2 ops
  unsigned int u = __builtin_bit_cast(unsigned int, f);
  return (unsigned short)((u + 0x8000u) >> 16);
}
static __device__ __forceinline__ float bf2f(unsigned short u) {
  return __builtin_bit_cast(float, (unsigned)u << 16);
}
static __device__ __forceinline__ float exp2_fast(float x) {   // v_exp_f32 IS 2^x
  float r;
  asm("v_exp_f32 %0, %1" : "=v"(r) : "v"(x));
  return r;
}
static __device__ __forceinline__ float log2_fast(float x) {   // v_log_f32 IS log2
  float r;
  asm("v_log_f32 %0, %1" : "=v"(r) : "v"(x));
  return r;
}
static __device__ __forceinline__ void gload16(const void* g, unsigned short* l) {
  __builtin_amdgcn_global_load_lds((const __attribute__((address_space(1))) void*)g,
                                   (__attribute__((address_space(3))) void*)l, 16, 0, 0);
}
// swizzled b128 read from a [64 rows x 128B] LDS tile (attn K/V): chunk = m ^ (row&7)
static __device__ __forceinline__ bf16x8 lds128(const unsigned short* base, int row, int m) {
  return *(const bf16x8*)((const char*)base + row * 128 + (((m) ^ (row & 7)) << 4));
}

// ---------- fp32 -> bf16 convert: all 7 tensors in one launch (z=0..6); nt loads ----------
__global__ __launch_bounds__(256) void cvt7_kernel(
    const float* __restrict__ x0, const float* __restrict__ x1, const float* __restrict__ x2,
    const float* __restrict__ w0, const float* __restrict__ w1, const float* __restrict__ w2,
    const float* __restrict__ w3,
    unsigned short* __restrict__ dx0, unsigned short* __restrict__ dx1,
    unsigned short* __restrict__ dx2, unsigned short* __restrict__ dw0,
    unsigned short* __restrict__ dw1, unsigned short* __restrict__ dw2,
    unsigned short* __restrict__ dw3, int nx4, int nw4) {
  const int z = blockIdx.y;
  const float* src;
  unsigned short* dst;
  int n4;
  switch (z) {
    case 0: src = x0; dst = dx0; n4 = nx4; break;
    case 1: src = x1; dst = dx1; n4 = nx4; break;
    case 2: src = x2; dst = dx2; n4 = nx4; break;
    case 3: src = w0; dst = dw0; n4 = nw4; break;
    case 4: src = w1; dst = dw1; n4 = nw4; break;
    case 5: src = w2; dst = dw2; n4 = nw4; break;
    default: src = w3; dst = dw3; n4 = nw4; break;
  }
  int i = blockIdx.x * 256 + threadIdx.x;
  if (i >= n4) return;
  f32x4 v = __builtin_nontemporal_load(reinterpret_cast<const f32x4*>(src) + i);
  ushort4 o;
  o.x = f2bf(v[0]); o.y = f2bf(v[1]); o.z = f2bf(v[2]); o.w = f2bf(v[3]);
  reinterpret_cast<ushort4*>(dst)[i] = o;
}

// ---------- pack mask to bits (inline dtype detection); nt loads on the int32 stream ----------
// word w covers flat row r = w/32, cols [(w%32)*64, +64)
__global__ __launch_bounds__(256) void mask_pack_kernel(const unsigned char* __restrict__ m8,
                                                        const int* __restrict__ m32,
                                                        unsigned long long* __restrict__ bits) {
  __shared__ int s;
  if (threadIdx.x == 0) s = 0;
  __syncthreads();
  {
    const unsigned int* mi = (const unsigned int*)m8;
    int any = 0;
#pragma unroll
    for (int i = 0; i < 4; ++i) any |= (mi[threadIdx.x + 256 * i] > 1u) ? 1 : 0;
    if (any) atomicOr(&s, 1);
  }
  __syncthreads();
  const int use8 = s;
  const int wid = blockIdx.x * 256 + threadIdx.x;   // 0..262143
  unsigned long long v = 0;
  if (use8) {
    const uchar4* p = (const uchar4*)(m8 + (size_t)wid * 64);
#pragma unroll
    for (int c = 0; c < 16; ++c) {
      uchar4 q = p[c];
      v |= ((unsigned long long)(q.x != 0)) << (c * 4 + 0);
      v |= ((unsigned long long)(q.y != 0)) << (c * 4 + 1);
      v |= ((unsigned long long)(q.z != 0)) << (c * 4 + 2);
      v |= ((unsigned long long)(q.w != 0)) << (c * 4 + 3);
    }
  } else {
    const i32x4* p = (const i32x4*)(m32 + (size_t)wid * 64);
#pragma unroll
    for (int c = 0; c < 16; ++c) {
      i32x4 q = __builtin_nontemporal_load(p + c);
      v |= ((unsigned long long)(q[0] != 0)) << (c * 4 + 0);
      v |= ((unsigned long long)(q[1] != 0)) << (c * 4 + 1);
      v |= ((unsigned long long)(q[2] != 0)) << (c * 4 + 2);
      v |= ((unsigned long long)(q[3] != 0)) << (c * 4 + 3);
    }
  }
  bits[wid] = v;
}

// ---------- 128x128 bf16 GEMM mainloop: C = A(MxK) * B(NxK)^T ----------
// double-buffered global_load_lds ring: stage i+1, compute i, one vmcnt(0)+barrier per K-step.
__device__ __forceinline__ void gemm128_main(const unsigned short* __restrict__ A,
                                             const unsigned short* __restrict__ B,
                                             int K, int row0, int col0,
                                             unsigned short* lds, f32x4 acc[4][4]) {
  const int tid  = threadIdx.x;
  const int w    = tid >> 6;
  const int lane = tid & 63;
  const int lr   = lane & 15;
  const int lk   = (lane >> 4) << 3;
  const int wm   = (w >> 1) << 6;
  const int wn   = (w & 1) << 6;
  unsigned short* As[2] = { lds, lds + 2 * 4096 };
  unsigned short* Bs[2] = { lds + 4096, lds + 3 * 4096 };
  const int r0 = tid >> 2;
  const int c0 = (tid & 3) << 3;
  const unsigned short* a0 = A + (size_t)(row0 + r0) * K + c0;
  const unsigned short* a1 = A + (size_t)(row0 + r0 + 64) * K + c0;
  const unsigned short* b0 = B + (size_t)(col0 + r0) * K + c0;
  const unsigned short* b1 = B + (size_t)(col0 + r0 + 64) * K + c0;
  const int NI = K >> 5;
  gload16(a0, &As[0][tid * 8]);
  gload16(a1, &As[0][(tid + 256) * 8]);
  gload16(b0, &Bs[0][tid * 8]);
  gload16(b1, &Bs[0][(tid + 256) * 8]);
  asm volatile("s_waitcnt vmcnt(0)" ::: "memory");
  __builtin_amdgcn_s_barrier();
  for (int i = 0; i < NI; ++i) {
    const int cur = i & 1;
    if (i + 1 < NI) {
      const int nk = (i + 1) << 5;
      gload16(a0 + nk, &As[cur ^ 1][tid * 8]);
      gload16(a1 + nk, &As[cur ^ 1][(tid + 256) * 8]);
      gload16(b0 + nk, &Bs[cur ^ 1][tid * 8]);
      gload16(b1 + nk, &Bs[cur ^ 1][(tid + 256) * 8]);
    }
    const unsigned short* Ab = As[cur];
    const unsigned short* Bb = Bs[cur];
    bf16x8 af[4], bfr[4];
#pragma unroll
    for (int mi = 0; mi < 4; ++mi) af[mi]  = *(const bf16x8*)&Ab[(wm + mi * 16 + lr) * 32 + lk];
#pragma unroll
    for (int ni = 0; ni < 4; ++ni) bfr[ni] = *(const bf16x8*)&Bb[(wn + ni * 16 + lr) * 32 + lk];
    __builtin_amdgcn_s_setprio(1);
#pragma unroll
    for (int mi = 0; mi < 4; ++mi)
#pragma unroll
      for (int ni = 0; ni < 4; ++ni)
        acc[mi][ni] = MFMA_BF16(af[mi], bfr[ni], acc[mi][ni]);
    __builtin_amdgcn_s_setprio(0);
    if (i + 1 < NI) {
      asm volatile("s_waitcnt vmcnt(0)" ::: "memory");
      __builtin_amdgcn_s_barrier();
    }
  }
}

// ---------- projection GEMM: z in {Q,K,V}. Q/K write [b,h,s,d]; V writes TRANSPOSED [b,h,d,s] ----------
__global__ __launch_bounds__(256) void proj_kernel(
    const unsigned short* __restrict__ Xq, const unsigned short* __restrict__ Xk,
    const unsigned short* __restrict__ Xv,
    const unsigned short* __restrict__ Wq, const unsigned short* __restrict__ Wk,
    const unsigned short* __restrict__ Wv,
    unsigned short* __restrict__ Qh, unsigned short* __restrict__ Kh,
    unsigned short* __restrict__ VT) {
  __shared__ __align__(16) unsigned short lds[4 * 4096];
  const int z = blockIdx.z;
  const unsigned short* A = (z == 0) ? Xq : ((z == 1) ? Xk : Xv);
  const unsigned short* B = (z == 0) ? Wq : ((z == 1) ? Wk : Wv);
  unsigned short* O       = (z == 0) ? Qh : ((z == 1) ? Kh : VT);
  const int row0 = blockIdx.x * 128, col0 = blockIdx.y * 128;
  f32x4 acc[4][4];
  const f32x4 zero = {0.f, 0.f, 0.f, 0.f};
#pragma unroll
  for (int mi = 0; mi < 4; ++mi)
#pragma unroll
    for (int ni = 0; ni < 4; ++ni) acc[mi][ni] = zero;
  gemm128_main(A, B, DM, row0, col0, lds, acc);
  const int w = threadIdx.x >> 6, lane = threadIdx.x & 63;
  const int lr = lane & 15, lg = lane >> 4;
  const int wm = (w >> 1) << 6, wn = (w & 1) << 6;
#pragma unroll
  for (int mi = 0; mi < 4; ++mi)
#pragma unroll
    for (int ni = 0; ni < 4; ++ni)
#pragma unroll
      for (int j = 0; j < 4; ++j) {
        const int m = row0 + wm + mi * 16 + lg * 4 + j;   // global row in [0,8192)
        const int n = col0 + wn + ni * 16 + lr;           // feature in [0,512)
        const int b = m >> 11, s = m & 2047;
        const int h = n >> 6,  d = n & 63;
        const unsigned short val = f2bf(acc[mi][ni][j]);
        if (z == 2)
          O[(((size_t)(b * NH + h)) * DK + d) * SEQ + s] = val;   // V^T: [b,h,d,s]
        else
          O[(((size_t)(b * NH + h)) * SEQ + s) * DK + d] = val;   // [b,h,s,d]
      }
}

// ---------- output projection GEMM: fp32 out, flat [8192][512] ----------
__global__ __launch_bounds__(256) void fc_kernel(const unsigned short* __restrict__ A,
                                                 const unsigned short* __restrict__ W,
                                                 float* __restrict__ Out) {
  __shared__ __align__(16) unsigned short lds[4 * 4096];
  const int row0 = blockIdx.x * 128, col0 = blockIdx.y * 128;
  f32x4 acc[4][4];
  const f32x4 zero = {0.f, 0.f, 0.f, 0.f};
#pragma unroll
  for (int mi = 0; mi < 4; ++mi)
#pragma unroll
    for (int ni = 0; ni < 4; ++ni) acc[mi][ni] = zero;
  gemm128_main(A, W, DM, row0, col0, lds, acc);
  const int w = threadIdx.x >> 6, lane = threadIdx.x & 63;
  const int lr = lane & 15, lg = lane >> 4;
  const int wm = (w >> 1) << 6, wn = (w & 1) << 6;
#pragma unroll
  for (int mi = 0; mi < 4; ++mi)
#pragma unroll
    for (int ni = 0; ni < 4; ++ni)
#pragma unroll
      for (int j = 0; j < 4; ++j) {
        const int m = row0 + wm + mi * 16 + lg * 4 + j;
        const int n = col0 + wn + ni * 16 + lr;
        Out[(size_t)m * DM + n] = acc[mi][ni][j];
      }
}

// ---------- fused attention: 4 waves x 2 q-subtiles; nt attn stores; setprio MFMA ----------
// grid (16, 8, 4) remapped XCD-aware; 256 threads = 4 waves x 32 q-rows
__global__ __launch_bounds__(256, 3) void attn_kernel(
    const unsigned short* __restrict__ Qh, const unsigned short* __restrict__ Kh,
    const unsigned short* __restrict__ VT, const unsigned long long* __restrict__ Mb,
    float* __restrict__ attn_out, unsigned short* __restrict__ R16) {
  __shared__ __align__(16) unsigned short Ks[2][KTDK];       // 2 x 8KB, chunk-swizzled
  __shared__ __align__(16) unsigned short Vs[2][KTDK];       // 2 x 8KB, chunk-swizzled
  __shared__ __align__(16) unsigned short Pl[4][2][16 * PS]; // per wave, per subtile
  const int id  = blockIdx.x + 16 * (blockIdx.y + 8 * blockIdx.z);   // 0..511
  const int q8  = id >> 3;
  const int bh  = (id & 7) * 4 + (q8 >> 4);   // 0..31 (same XCD per bh)
  const int qt  = q8 & 15;                    // 0..15
  const int b   = bh >> 3;
  const int tid = threadIdx.x, w = tid >> 6, lane = tid & 63;
  const int lr = lane & 15, lg = lane >> 4;
  const unsigned short* Qp = Qh + (size_t)bh * SEQ * DK;
  const unsigned short* Kp = Kh + (size_t)bh * SEQ * DK;
  const unsigned short* Vp = VT + (size_t)bh * DK * SEQ;   // [d][s]
  float* ap = attn_out + (size_t)bh * SEQ * SEQ;

  const int qbA = qt * QB + w * 32;     // subtile A: rows qbA..qbA+15
  const int qbB = qbA + 16;             // subtile B: rows qbB..qbB+15
  const bf16x8 qfA0 = *(const bf16x8*)(Qp + (size_t)(qbA + lr) * DK + lg * 8);
  const bf16x8 qfA1 = *(const bf16x8*)(Qp + (size_t)(qbA + lr) * DK + 32 + lg * 8);
  const bf16x8 qfB0 = *(const bf16x8*)(Qp + (size_t)(qbB + lr) * DK + lg * 8);
  const bf16x8 qfB1 = *(const bf16x8*)(Qp + (size_t)(qbB + lr) * DK + 32 + lg * 8);
  const unsigned long long* mrowA = Mb + ((size_t)b * SEQ + qbA + lr) * 32;
  const unsigned long long* mrowB = Mb + ((size_t)b * SEQ + qbB + lr) * 32;

  // staging: 256 threads x 2 chunks per 8KB buffer (dest-linear, source pre-swizzled)
  const int ci0 = tid, ci1 = tid + 256;
  const int sr0 = ci0 >> 3, sc0 = (ci0 & 7) ^ (sr0 & 7);
  const int sr1 = ci1 >> 3, sc1 = (ci1 & 7) ^ (sr1 & 7);
  const unsigned short* kst0 = Kp + (size_t)sr0 * DK + sc0 * 8;
  const unsigned short* kst1 = Kp + (size_t)sr1 * DK + sc1 * 8;
  const unsigned short* vst0 = Vp + (size_t)sr0 * SEQ + sc0 * 8;
  const unsigned short* vst1 = Vp + (size_t)sr1 * SEQ + sc1 * 8;

  // ================= pass 1: row sums in exp2 domain (staged K, shared reads) =================
  float l2A = 0.f, l2B = 0.f;
  gload16(kst0, &Ks[0][ci0 * 8]);
  gload16(kst1, &Ks[0][ci1 * 8]);
  __syncthreads();
  for (int t = 0; t < NT; ++t) {
    const unsigned short* Kb = Ks[t & 1];
    if (t + 1 < NT) {
      gload16(kst0 + (size_t)(t + 1) * KTDK, &Ks[(t & 1) ^ 1][ci0 * 8]);
      gload16(kst1 + (size_t)(t + 1) * KTDK, &Ks[(t & 1) ^ 1][ci1 * 8]);
    }
    const unsigned long long mrA = mrowA[t];
    const unsigned long long mrB = mrowB[t];
#pragma unroll
    for (int ni = 0; ni < 4; ++ni) {
      const int r = ni * 16 + lr;
      bf16x8 k0 = lds128(Kb, r, lg);
      bf16x8 k1 = lds128(Kb, r, lg + 4);
      __builtin_amdgcn_s_setprio(1);
      f32x4 zA = {0.f, 0.f, 0.f, 0.f};
      zA = MFMA_BF16(k0, qfA0, zA);
      zA = MFMA_BF16(k1, qfA1, zA);
      f32x4 zB = {0.f, 0.f, 0.f, 0.f};
      zB = MFMA_BF16(k0, qfB0, zB);
      zB = MFMA_BF16(k1, qfB1, zB);
      __builtin_amdgcn_s_setprio(0);
#pragma unroll
      for (int j = 0; j < 4; ++j) {
        const int bit = ni * 16 + lg * 4 + j;
        const float xA = ((mrA >> bit) & 1ull) ? MASKED_X : zA[j] * C2LOG2E;
        const float xB = ((mrB >> bit) & 1ull) ? MASKED_X : zB[j] * C2LOG2E;
        l2A += exp2_fast(xA);
        l2B += exp2_fast(xB);
      }
    }
    __syncthreads();
  }
  l2A += __shfl_xor(l2A, 16);
  l2A += __shfl_xor(l2A, 32);
  l2B += __shfl_xor(l2B, 16);
  l2B += __shfl_xor(l2B, 32);
  const float negllogA = -log2_fast(l2A);
  const float negllogB = -log2_fast(l2B);
  const float mAltA = MASKED_X + negllogA;
  const float mAltB = MASKED_X + negllogB;

  // ================= pass 2: P write + PV + attn store; counted-vmcnt barriers =================
  f32x4 oA[4], oB[4];
  const f32x4 zero = {0.f, 0.f, 0.f, 0.f};
#pragma unroll
  for (int nd = 0; nd < 4; ++nd) { oA[nd] = zero; oB[nd] = zero; }
  unsigned short* PwA = &Pl[w][0][0];
  unsigned short* PwB = &Pl[w][1][0];

  gload16(kst0, &Ks[0][ci0 * 8]);
  gload16(kst1, &Ks[0][ci1 * 8]);
  gload16(vst0, &Vs[0][ci0 * 8]);
  gload16(vst1, &Vs[0][ci1 * 8]);
  asm volatile("s_waitcnt vmcnt(0)" ::: "memory");
  __builtin_amdgcn_s_barrier();
  for (int t = 0; t < NT; ++t) {
    const unsigned short* Kb = Ks[t & 1];
    const unsigned short* Vb = Vs[t & 1];
    if (t + 1 < NT) {
      gload16(kst0 + (size_t)(t + 1) * KTDK, &Ks[(t & 1) ^ 1][ci0 * 8]);
      gload16(kst1 + (size_t)(t + 1) * KTDK, &Ks[(t & 1) ^ 1][ci1 * 8]);
      gload16(vst0 + (size_t)(t + 1) * KT,   &Vs[(t & 1) ^ 1][ci0 * 8]);
      gload16(vst1 + (size_t)(t + 1) * KT,   &Vs[(t & 1) ^ 1][ci1 * 8]);
    }
    const unsigned long long mrA = mrowA[t];
    const unsigned long long mrB = mrowB[t];
    // --- QK^T (swapped), K fragments shared across both subtiles ---
#pragma unroll
    for (int ni = 0; ni < 4; ++ni) {
      const int r = ni * 16 + lr;
      bf16x8 k0 = lds128(Kb, r, lg);
      bf16x8 k1 = lds128(Kb, r, lg + 4);
      __builtin_amdgcn_s_setprio(1);
      f32x4 zA = {0.f, 0.f, 0.f, 0.f};
      zA = MFMA_BF16(k0, qfA0, zA);
      zA = MFMA_BF16(k1, qfA1, zA);
      f32x4 zB = {0.f, 0.f, 0.f, 0.f};
      zB = MFMA_BF16(k0, qfB0, zB);
      zB = MFMA_BF16(k1, qfB1, zB);
      __builtin_amdgcn_s_setprio(0);
      float pA[4], pB[4];
#pragma unroll
      for (int j = 0; j < 4; ++j) {
        const int bit = ni * 16 + lg * 4 + j;
        const float xA = ((mrA >> bit) & 1ull) ? mAltA : fmaf(zA[j], C2LOG2E, negllogA);
        const float xB = ((mrB >> bit) & 1ull) ? mAltB : fmaf(zB[j], C2LOG2E, negllogB);
        pA[j] = exp2_fast(xA);
        pB[j] = exp2_fast(xB);
      }
      ushort4 pkA = {rhu(pA[0]), rhu(pA[1]), rhu(pA[2]), rhu(pA[3])};
      ushort4 pkB = {rhu(pB[0]), rhu(pB[1]), rhu(pB[2]), rhu(pB[3])};
      *(ushort4*)&PwA[lr * PS + ni * 16 + lg * 4] = pkA;
      *(ushort4*)&PwB[lr * PS + ni * 16 + lg * 4] = pkB;
    }
    // --- PV: V fragments shared across both subtiles ---
    const bf16x8 pfA0 = *(const bf16x8*)&PwA[lr * PS + lg * 8];
    const bf16x8 pfA1 = *(const bf16x8*)&PwA[lr * PS + 32 + lg * 8];
    const bf16x8 pfB0 = *(const bf16x8*)&PwB[lr * PS + lg * 8];
    const bf16x8 pfB1 = *(const bf16x8*)&PwB[lr * PS + 32 + lg * 8];
    __builtin_amdgcn_s_setprio(1);
#pragma unroll
    for (int nd = 0; nd < 4; ++nd) {
      const int r = nd * 16 + lr;
      bf16x8 v0 = lds128(Vb, r, lg);
      bf16x8 v1 = lds128(Vb, r, lg + 4);
      oA[nd] = MFMA_BF16(pfA0, v0, oA[nd]);
      oA[nd] = MFMA_BF16(pfA1, v1, oA[nd]);
      oB[nd] = MFMA_BF16(pfB0, v0, oB[nd]);
      oB[nd] = MFMA_BF16(pfB1, v1, oB[nd]);
    }
    __builtin_amdgcn_s_setprio(0);
    // --- attn fp32 stores: verified pattern (row from lg, col from lr), NONTEMPORAL ---
#pragma unroll
    for (int j = 0; j < 4; ++j) {
      const int r = lg * 4 + j;
      ushort4 pkA = *(const ushort4*)&PwA[r * PS + lr * 4];
      f32x4 fA = {bf2f(pkA.x), bf2f(pkA.y), bf2f(pkA.z), bf2f(pkA.w)};
      __builtin_nontemporal_store(fA, (f32x4*)(ap + (size_t)(qbA + r) * SEQ + t * KT + lr * 4));
      ushort4 pkB = *(const ushort4*)&PwB[r * PS + lr * 4];
      f32x4 fB = {bf2f(pkB.x), bf2f(pkB.y), bf2f(pkB.z), bf2f(pkB.w)};
      __builtin_nontemporal_store(fB, (f32x4*)(ap + (size_t)(qbB + r) * SEQ + t * KT + lr * 4));
    }
    // --- counted-vmcnt barrier: wait the 4 gloads (t+1), leave the 8 newest stores in flight ---
    if (t + 1 < NT) {
      asm volatile("s_waitcnt vmcnt(8)" ::: "memory");
      __builtin_amdgcn_s_barrier();
    }
  }
  // ---- epilogue: write result in [b*S+s][h*64+d] bf16 layout, both subtiles ----
#pragma unroll
  for (int nd = 0; nd < 4; ++nd)
#pragma unroll
    for (int j = 0; j < 4; ++j) {
      R16[((size_t)(b * SEQ + qbA + lg * 4 + j)) * DM + (bh & 7) * DK + nd * 16 + lr] = f2bf(oA[nd][j]);
      R16[((size_t)(b * SEQ + qbB + lg * 4 + j)) * DM + (bh & 7) * DK + nd * 16 + lr] = f2bf(oB[nd][j]);
    }
}

// ---------- residual + LayerNorm (one wave per row); nt output stores ----------
__global__ __launch_bounds__(256) void ln_kernel(const float* __restrict__ fc,
                                                 const float* __restrict__ xq,
                                                 const float* __restrict__ gamma,
                                                 const float* __restrict__ beta,
                                                 float* __restrict__ out) {
  const int row = blockIdx.x * 4 + (threadIdx.x >> 6);
  const int lane = threadIdx.x & 63;
  const float* f = fc + (size_t)row * DM;
  const float* x = xq + (size_t)row * DM;
  float v[8];
  float s = 0.f, ss = 0.f;
#pragma unroll
  for (int i = 0; i < 8; ++i) {
    const int c = lane + i * 64;
    const float t = f[c] + x[c];
    v[i] = t; s += t; ss += t * t;
  }
#pragma unroll
  for (int off = 1; off < 64; off <<= 1) {
    s  += __shfl_xor(s, off);
    ss += __shfl_xor(ss, off);
  }
  const float mu  = s * (1.f / 512.f);
  const float var = ss * (1.f / 512.f) - mu * mu;
  const float inv = rsqrtf(var + 1e-5f);
  float* op = out + (size_t)row * DM;
#pragma unroll
  for (int i = 0; i < 8; ++i) {
    const int c = lane + i * 64;
    __builtin_nontemporal_store((v[i] - mu) * inv * gamma[c] + beta[c], op + c);
  }
}

// ---------- workspace layout (bytes) ----------
// phase A: XQ16 0, XK16 8388608, XV16 16777216, WQ16 25165824, WK16 25690112,
//          WV16 26214400, WF16 26738688, Qh 27262976, Kh 35651584, VT 44040192
// phase B (X dead): Mbits @0 (2MB), R16 @16777216 (8.4MB)
// phase C (Qh/Kh dead): FC32 @27262976 (16.7MB).

extern "C" void kernel_launch(void* const* d_in, const int* in_sizes, int n_in,
                              void* d_out, int out_size, void* d_ws, size_t ws_size,
                              hipStream_t stream) {
  const float* xq   = (const float*)d_in[0];
  const float* xk   = (const float*)d_in[1];
  const float* xv   = (const float*)d_in[2];
  const void*  mask = d_in[3];
  const float* wq   = (const float*)d_in[4];
  const float* wk   = (const float*)d_in[5];
  const float* wv   = (const float*)d_in[6];
  const float* wfc  = (const float*)d_in[7];
  const float* gamma = (const float*)d_in[8];
  const float* beta  = (const float*)d_in[9];

  float* out = (float*)d_out;
  float* attn_out = out + (size_t)BDIM * SEQ * DM;

  char* ws = (char*)d_ws;
  unsigned short* XQ16 = (unsigned short*)(ws);
  unsigned short* XK16 = (unsigned short*)(ws + 8388608);
  unsigned short* XV16 = (unsigned short*)(ws + 16777216);
  unsigned short* WQ16 = (unsigned short*)(ws + 25165824);
  unsigned short* WK16 = (unsigned short*)(ws + 25690112);
  unsigned short* WV16 = (unsigned short*)(ws + 26214400);
  unsigned short* WF16 = (unsigned short*)(ws + 26738688);
  unsigned short* Qh   = (unsigned short*)(ws + 27262976);
  unsigned short* Kh   = (unsigned short*)(ws + 35651584);
  unsigned short* VT   = (unsigned short*)(ws + 44040192);
  unsigned long long* Mbits = (unsigned long long*)(ws);        // reuse XQ16 (2MB)
  unsigned short* R16  = (unsigned short*)(ws + 16777216);      // reuse XV16
  float*          FC32 = (float*)(ws + 27262976);               // reuse Qh/Kh

  const int NX4 = BDIM * SEQ * DM / 4;   // 1,048,576
  const int NW4 = DM * DM / 4;           // 65,536

  cvt7_kernel<<<dim3(NX4 / 256, 7), 256, 0, stream>>>(xq, xk, xv, wq, wk, wv, wfc,
                                                      XQ16, XK16, XV16,
                                                      WQ16, WK16, WV16, WF16, NX4, NW4);
  proj_kernel<<<dim3(64, 4, 3), 256, 0, stream>>>(XQ16, XK16, XV16,
                                                  WQ16, WK16, WV16, Qh, Kh, VT);
  mask_pack_kernel<<<1024, 256, 0, stream>>>((const unsigned char*)mask,
                                             (const int*)mask, Mbits);
  attn_kernel<<<dim3(16, NH, BDIM), 256, 0, stream>>>(Qh, Kh, VT, Mbits, attn_out, R16);
  fc_kernel<<<dim3(64, 4, 1), 256, 0, stream>>>(R16, WF16, FC32);
  ln_kernel<<<2048, 256, 0, stream>>>(FC32, xq, gamma, beta, out);
}

// Round 18
// 260.143 us; speedup vs baseline: 1.0297x; 1.0297x over previous
//
#include <hip/hip_runtime.h>

typedef float  f32x4  __attribute__((ext_vector_type(4)));
typedef int    i32x4  __attribute__((ext_vector_type(4)));
typedef __bf16 bf16x8 __attribute__((ext_vector_type(8)));

#define MFMA_BF16(a, b, c) __builtin_amdgcn_mfma_f32_16x16x32_bf16((a), (b), (c), 0, 0, 0)

// ---------- constants ----------
#define BDIM   4
#define SEQ    2048
#define DM     512
#define NH     8
#define DK     64
#define KT     64           // k-tile
#define NT     (SEQ / KT)   // 32
#define QB     128          // q-rows per block (4 waves x 2 subtiles x 16)
#define PS     72           // P-tile LDS stride (shorts)
#define KTDK   (KT * DK)    // shorts per K tile
// softmax in exp2 domain: exp(s*0.125) = exp2(s * 0.125*log2(e))
#define C2LOG2E  0.18033688011112042f
#define MASKED_X (-115.41560327111707f)   // -80 * log2(e); exp2 -> 2.37e-35 (normal)

static __device__ __forceinline__ unsigned short f2bf(float f) {
  unsigned int u = __builtin_bit_cast(unsigned int, f);
  u += 0x7fffu + ((u >> 16) & 1u);   // round-to-nearest-even
  return (unsigned short)(u >> 16);
}
static __device__ __forceinline__ unsigned short rhu(float f) {   // round-half-up, 2 ops
  unsigned int u = __builtin_bit_cast(unsigned int, f);
  return (unsigned short)((u + 0x8000u) >> 16);
}
static __device__ __forceinline__ float bf2f(unsigned short u) {
  return __builtin_bit_cast(float, (unsigned)u << 16);
}
static __device__ __forceinline__ float exp2_fast(float x) {   // v_exp_f32 IS 2^x
  float r;
  asm("v_exp_f32 %0, %1" : "=v"(r) : "v"(x));
  return r;
}
static __device__ __forceinline__ float log2_fast(float x) {   // v_log_f32 IS log2
  float r;
  asm("v_log_f32 %0, %1" : "=v"(r) : "v"(x));
  return r;
}
static __device__ __forceinline__ void gload16(const void* g, unsigned short* l) {
  __builtin_amdgcn_global_load_lds((const __attribute__((address_space(1))) void*)g,
                                   (__attribute__((address_space(3))) void*)l, 16, 0, 0);
}
// swizzled b128 read from a [64 rows x 128B] LDS tile (attn K/V): chunk = m ^ (row&7)
static __device__ __forceinline__ bf16x8 lds128(const unsigned short* base, int row, int m) {
  return *(const bf16x8*)((const char*)base + row * 128 + (((m) ^ (row & 7)) << 4));
}

// ---------- fp32 -> bf16 convert: all 7 tensors in one launch (z=0..6); nt loads ----------
__global__ __launch_bounds__(256) void cvt7_kernel(
    const float* __restrict__ x0, const float* __restrict__ x1, const float* __restrict__ x2,
    const float* __restrict__ w0, const float* __restrict__ w1, const float* __restrict__ w2,
    const float* __restrict__ w3,
    unsigned short* __restrict__ dx0, unsigned short* __restrict__ dx1,
    unsigned short* __restrict__ dx2, unsigned short* __restrict__ dw0,
    unsigned short* __restrict__ dw1, unsigned short* __restrict__ dw2,
    unsigned short* __restrict__ dw3, int nx4, int nw4) {
  const int z = blockIdx.y;
  const float* src;
  unsigned short* dst;
  int n4;
  switch (z) {
    case 0: src = x0; dst = dx0; n4 = nx4; break;
    case 1: src = x1; dst = dx1; n4 = nx4; break;
    case 2: src = x2; dst = dx2; n4 = nx4; break;
    case 3: src = w0; dst = dw0; n4 = nw4; break;
    case 4: src = w1; dst = dw1; n4 = nw4; break;
    case 5: src = w2; dst = dw2; n4 = nw4; break;
    default: src = w3; dst = dw3; n4 = nw4; break;
  }
  int i = blockIdx.x * 256 + threadIdx.x;
  if (i >= n4) return;
  f32x4 v = __builtin_nontemporal_load(reinterpret_cast<const f32x4*>(src) + i);
  ushort4 o;
  o.x = f2bf(v[0]); o.y = f2bf(v[1]); o.z = f2bf(v[2]); o.w = f2bf(v[3]);
  reinterpret_cast<ushort4*>(dst)[i] = o;
}

// ---------- pack mask to bits (inline dtype detection); nt loads on the int32 stream ----------
// word w covers flat row r = w/32, cols [(w%32)*64, +64)
__global__ __launch_bounds__(256) void mask_pack_kernel(const unsigned char* __restrict__ m8,
                                                        const int* __restrict__ m32,
                                                        unsigned long long* __restrict__ bits) {
  __shared__ int s;
  if (threadIdx.x == 0) s = 0;
  __syncthreads();
  {
    const unsigned int* mi = (const unsigned int*)m8;
    int any = 0;
#pragma unroll
    for (int i = 0; i < 4; ++i) any |= (mi[threadIdx.x + 256 * i] > 1u) ? 1 : 0;
    if (any) atomicOr(&s, 1);
  }
  __syncthreads();
  const int use8 = s;
  const int wid = blockIdx.x * 256 + threadIdx.x;   // 0..262143
  unsigned long long v = 0;
  if (use8) {
    const uchar4* p = (const uchar4*)(m8 + (size_t)wid * 64);
#pragma unroll
    for (int c = 0; c < 16; ++c) {
      uchar4 q = p[c];
      v |= ((unsigned long long)(q.x != 0)) << (c * 4 + 0);
      v |= ((unsigned long long)(q.y != 0)) << (c * 4 + 1);
      v |= ((unsigned long long)(q.z != 0)) << (c * 4 + 2);
      v |= ((unsigned long long)(q.w != 0)) << (c * 4 + 3);
    }
  } else {
    const i32x4* p = (const i32x4*)(m32 + (size_t)wid * 64);
#pragma unroll
    for (int c = 0; c < 16; ++c) {
      i32x4 q = __builtin_nontemporal_load(p + c);
      v |= ((unsigned long long)(q[0] != 0)) << (c * 4 + 0);
      v |= ((unsigned long long)(q[1] != 0)) << (c * 4 + 1);
      v |= ((unsigned long long)(q[2] != 0)) << (c * 4 + 2);
      v |= ((unsigned long long)(q[3] != 0)) << (c * 4 + 3);
    }
  }
  bits[wid] = v;
}

// ---------- 128x128 bf16 GEMM mainloop: C = A(MxK) * B(NxK)^T ----------
// double-buffered global_load_lds ring: stage i+1, compute i, one vmcnt(0)+barrier per K-step.
__device__ __forceinline__ void gemm128_main(const unsigned short* __restrict__ A,
                                             const unsigned short* __restrict__ B,
                                             int K, int row0, int col0,
                                             unsigned short* lds, f32x4 acc[4][4]) {
  const int tid  = threadIdx.x;
  const int w    = tid >> 6;
  const int lane = tid & 63;
  const int lr   = lane & 15;
  const int lk   = (lane >> 4) << 3;
  const int wm   = (w >> 1) << 6;
  const int wn   = (w & 1) << 6;
  unsigned short* As[2] = { lds, lds + 2 * 4096 };
  unsigned short* Bs[2] = { lds + 4096, lds + 3 * 4096 };
  const int r0 = tid >> 2;
  const int c0 = (tid & 3) << 3;
  const unsigned short* a0 = A + (size_t)(row0 + r0) * K + c0;
  const unsigned short* a1 = A + (size_t)(row0 + r0 + 64) * K + c0;
  const unsigned short* b0 = B + (size_t)(col0 + r0) * K + c0;
  const unsigned short* b1 = B + (size_t)(col0 + r0 + 64) * K + c0;
  const int NI = K >> 5;
  gload16(a0, &As[0][tid * 8]);
  gload16(a1, &As[0][(tid + 256) * 8]);
  gload16(b0, &Bs[0][tid * 8]);
  gload16(b1, &Bs[0][(tid + 256) * 8]);
  asm volatile("s_waitcnt vmcnt(0)" ::: "memory");
  __builtin_amdgcn_s_barrier();
  for (int i = 0; i < NI; ++i) {
    const int cur = i & 1;
    if (i + 1 < NI) {
      const int nk = (i + 1) << 5;
      gload16(a0 + nk, &As[cur ^ 1][tid * 8]);
      gload16(a1 + nk, &As[cur ^ 1][(tid + 256) * 8]);
      gload16(b0 + nk, &Bs[cur ^ 1][tid * 8]);
      gload16(b1 + nk, &Bs[cur ^ 1][(tid + 256) * 8]);
    }
    const unsigned short* Ab = As[cur];
    const unsigned short* Bb = Bs[cur];
    bf16x8 af[4], bfr[4];
#pragma unroll
    for (int mi = 0; mi < 4; ++mi) af[mi]  = *(const bf16x8*)&Ab[(wm + mi * 16 + lr) * 32 + lk];
#pragma unroll
    for (int ni = 0; ni < 4; ++ni) bfr[ni] = *(const bf16x8*)&Bb[(wn + ni * 16 + lr) * 32 + lk];
#pragma unroll
    for (int mi = 0; mi < 4; ++mi)
#pragma unroll
      for (int ni = 0; ni < 4; ++ni)
        acc[mi][ni] = MFMA_BF16(af[mi], bfr[ni], acc[mi][ni]);
    if (i + 1 < NI) {
      asm volatile("s_waitcnt vmcnt(0)" ::: "memory");
      __builtin_amdgcn_s_barrier();
    }
  }
}

// ---------- projection GEMM: z in {Q,K,V}. Q/K write [b,h,s,d]; V writes TRANSPOSED [b,h,d,s] ----------
__global__ __launch_bounds__(256) void proj_kernel(
    const unsigned short* __restrict__ Xq, const unsigned short* __restrict__ Xk,
    const unsigned short* __restrict__ Xv,
    const unsigned short* __restrict__ Wq, const unsigned short* __restrict__ Wk,
    const unsigned short* __restrict__ Wv,
    unsigned short* __restrict__ Qh, unsigned short* __restrict__ Kh,
    unsigned short* __restrict__ VT) {
  __shared__ __align__(16) unsigned short lds[4 * 4096];
  const int z = blockIdx.z;
  const unsigned short* A = (z == 0) ? Xq : ((z == 1) ? Xk : Xv);
  const unsigned short* B = (z == 0) ? Wq : ((z == 1) ? Wk : Wv);
  unsigned short* O       = (z == 0) ? Qh : ((z == 1) ? Kh : VT);
  const int row0 = blockIdx.x * 128, col0 = blockIdx.y * 128;
  f32x4 acc[4][4];
  const f32x4 zero = {0.f, 0.f, 0.f, 0.f};
#pragma unroll
  for (int mi = 0; mi < 4; ++mi)
#pragma unroll
    for (int ni = 0; ni < 4; ++ni) acc[mi][ni] = zero;
  gemm128_main(A, B, DM, row0, col0, lds, acc);
  const int w = threadIdx.x >> 6, lane = threadIdx.x & 63;
  const int lr = lane & 15, lg = lane >> 4;
  const int wm = (w >> 1) << 6, wn = (w & 1) << 6;
#pragma unroll
  for (int mi = 0; mi < 4; ++mi)
#pragma unroll
    for (int ni = 0; ni < 4; ++ni)
#pragma unroll
      for (int j = 0; j < 4; ++j) {
        const int m = row0 + wm + mi * 16 + lg * 4 + j;   // global row in [0,8192)
        const int n = col0 + wn + ni * 16 + lr;           // feature in [0,512)
        const int b = m >> 11, s = m & 2047;
        const int h = n >> 6,  d = n & 63;
        const unsigned short val = f2bf(acc[mi][ni][j]);
        if (z == 2)
          O[(((size_t)(b * NH + h)) * DK + d) * SEQ + s] = val;   // V^T: [b,h,d,s]
        else
          O[(((size_t)(b * NH + h)) * SEQ + s) * DK + d] = val;   // [b,h,s,d]
      }
}

// ---------- output projection GEMM: fp32 out, flat [8192][512] ----------
__global__ __launch_bounds__(256) void fc_kernel(const unsigned short* __restrict__ A,
                                                 const unsigned short* __restrict__ W,
                                                 float* __restrict__ Out) {
  __shared__ __align__(16) unsigned short lds[4 * 4096];
  const int row0 = blockIdx.x * 128, col0 = blockIdx.y * 128;
  f32x4 acc[4][4];
  const f32x4 zero = {0.f, 0.f, 0.f, 0.f};
#pragma unroll
  for (int mi = 0; mi < 4; ++mi)
#pragma unroll
    for (int ni = 0; ni < 4; ++ni) acc[mi][ni] = zero;
  gemm128_main(A, W, DM, row0, col0, lds, acc);
  const int w = threadIdx.x >> 6, lane = threadIdx.x & 63;
  const int lr = lane & 15, lg = lane >> 4;
  const int wm = (w >> 1) << 6, wn = (w & 1) << 6;
#pragma unroll
  for (int mi = 0; mi < 4; ++mi)
#pragma unroll
    for (int ni = 0; ni < 4; ++ni)
#pragma unroll
      for (int j = 0; j < 4; ++j) {
        const int m = row0 + wm + mi * 16 + lg * 4 + j;
        const int n = col0 + wn + ni * 16 + lr;
        Out[(size_t)m * DM + n] = acc[mi][ni][j];
      }
}

// ---------- fused attention: 4 waves x 2 q-subtiles; nontemporal attn stores ----------
// grid (16, 8, 4) remapped XCD-aware; 256 threads = 4 waves x 32 q-rows
__global__ __launch_bounds__(256, 3) void attn_kernel(
    const unsigned short* __restrict__ Qh, const unsigned short* __restrict__ Kh,
    const unsigned short* __restrict__ VT, const unsigned long long* __restrict__ Mb,
    float* __restrict__ attn_out, unsigned short* __restrict__ R16) {
  __shared__ __align__(16) unsigned short Ks[2][KTDK];       // 2 x 8KB, chunk-swizzled
  __shared__ __align__(16) unsigned short Vs[2][KTDK];       // 2 x 8KB, chunk-swizzled
  __shared__ __align__(16) unsigned short Pl[4][2][16 * PS]; // per wave, per subtile
  const int id  = blockIdx.x + 16 * (blockIdx.y + 8 * blockIdx.z);   // 0..511
  const int q8  = id >> 3;
  const int bh  = (id & 7) * 4 + (q8 >> 4);   // 0..31 (same XCD per bh)
  const int qt  = q8 & 15;                    // 0..15
  const int b   = bh >> 3;
  const int tid = threadIdx.x, w = tid >> 6, lane = tid & 63;
  const int lr = lane & 15, lg = lane >> 4;
  const unsigned short* Qp = Qh + (size_t)bh * SEQ * DK;
  const unsigned short* Kp = Kh + (size_t)bh * SEQ * DK;
  const unsigned short* Vp = VT + (size_t)bh * DK * SEQ;   // [d][s]
  float* ap = attn_out + (size_t)bh * SEQ * SEQ;

  const int qbA = qt * QB + w * 32;     // subtile A: rows qbA..qbA+15
  const int qbB = qbA + 16;             // subtile B: rows qbB..qbB+15
  const bf16x8 qfA0 = *(const bf16x8*)(Qp + (size_t)(qbA + lr) * DK + lg * 8);
  const bf16x8 qfA1 = *(const bf16x8*)(Qp + (size_t)(qbA + lr) * DK + 32 + lg * 8);
  const bf16x8 qfB0 = *(const bf16x8*)(Qp + (size_t)(qbB + lr) * DK + lg * 8);
  const bf16x8 qfB1 = *(const bf16x8*)(Qp + (size_t)(qbB + lr) * DK + 32 + lg * 8);
  const unsigned long long* mrowA = Mb + ((size_t)b * SEQ + qbA + lr) * 32;
  const unsigned long long* mrowB = Mb + ((size_t)b * SEQ + qbB + lr) * 32;

  // staging: 256 threads x 2 chunks per 8KB buffer (dest-linear, source pre-swizzled)
  const int ci0 = tid, ci1 = tid + 256;
  const int sr0 = ci0 >> 3, sc0 = (ci0 & 7) ^ (sr0 & 7);
  const int sr1 = ci1 >> 3, sc1 = (ci1 & 7) ^ (sr1 & 7);
  const unsigned short* kst0 = Kp + (size_t)sr0 * DK + sc0 * 8;
  const unsigned short* kst1 = Kp + (size_t)sr1 * DK + sc1 * 8;
  const unsigned short* vst0 = Vp + (size_t)sr0 * SEQ + sc0 * 8;
  const unsigned short* vst1 = Vp + (size_t)sr1 * SEQ + sc1 * 8;

  // ================= pass 1: row sums in exp2 domain (staged K, shared reads) =================
  float l2A = 0.f, l2B = 0.f;
  gload16(kst0, &Ks[0][ci0 * 8]);
  gload16(kst1, &Ks[0][ci1 * 8]);
  __syncthreads();
  for (int t = 0; t < NT; ++t) {
    const unsigned short* Kb = Ks[t & 1];
    if (t + 1 < NT) {
      gload16(kst0 + (size_t)(t + 1) * KTDK, &Ks[(t & 1) ^ 1][ci0 * 8]);
      gload16(kst1 + (size_t)(t + 1) * KTDK, &Ks[(t & 1) ^ 1][ci1 * 8]);
    }
    const unsigned long long mrA = mrowA[t];
    const unsigned long long mrB = mrowB[t];
#pragma unroll
    for (int ni = 0; ni < 4; ++ni) {
      const int r = ni * 16 + lr;
      bf16x8 k0 = lds128(Kb, r, lg);
      bf16x8 k1 = lds128(Kb, r, lg + 4);
      f32x4 zA = {0.f, 0.f, 0.f, 0.f};
      zA = MFMA_BF16(k0, qfA0, zA);
      zA = MFMA_BF16(k1, qfA1, zA);
      f32x4 zB = {0.f, 0.f, 0.f, 0.f};
      zB = MFMA_BF16(k0, qfB0, zB);
      zB = MFMA_BF16(k1, qfB1, zB);
#pragma unroll
      for (int j = 0; j < 4; ++j) {
        const int bit = ni * 16 + lg * 4 + j;
        const float xA = ((mrA >> bit) & 1ull) ? MASKED_X : zA[j] * C2LOG2E;
        const float xB = ((mrB >> bit) & 1ull) ? MASKED_X : zB[j] * C2LOG2E;
        l2A += exp2_fast(xA);
        l2B += exp2_fast(xB);
      }
    }
    __syncthreads();
  }
  l2A += __shfl_xor(l2A, 16);
  l2A += __shfl_xor(l2A, 32);
  l2B += __shfl_xor(l2B, 16);
  l2B += __shfl_xor(l2B, 32);
  const float negllogA = -log2_fast(l2A);
  const float negllogB = -log2_fast(l2B);
  const float mAltA = MASKED_X + negllogA;
  const float mAltB = MASKED_X + negllogB;

  // ================= pass 2: P write + PV + attn store; counted-vmcnt barriers =================
  f32x4 oA[4], oB[4];
  const f32x4 zero = {0.f, 0.f, 0.f, 0.f};
#pragma unroll
  for (int nd = 0; nd < 4; ++nd) { oA[nd] = zero; oB[nd] = zero; }
  unsigned short* PwA = &Pl[w][0][0];
  unsigned short* PwB = &Pl[w][1][0];

  gload16(kst0, &Ks[0][ci0 * 8]);
  gload16(kst1, &Ks[0][ci1 * 8]);
  gload16(vst0, &Vs[0][ci0 * 8]);
  gload16(vst1, &Vs[0][ci1 * 8]);
  asm volatile("s_waitcnt vmcnt(0)" ::: "memory");
  __builtin_amdgcn_s_barrier();
  for (int t = 0; t < NT; ++t) {
    const unsigned short* Kb = Ks[t & 1];
    const unsigned short* Vb = Vs[t & 1];
    if (t + 1 < NT) {
      gload16(kst0 + (size_t)(t + 1) * KTDK, &Ks[(t & 1) ^ 1][ci0 * 8]);
      gload16(kst1 + (size_t)(t + 1) * KTDK, &Ks[(t & 1) ^ 1][ci1 * 8]);
      gload16(vst0 + (size_t)(t + 1) * KT,   &Vs[(t & 1) ^ 1][ci0 * 8]);
      gload16(vst1 + (size_t)(t + 1) * KT,   &Vs[(t & 1) ^ 1][ci1 * 8]);
    }
    const unsigned long long mrA = mrowA[t];
    const unsigned long long mrB = mrowB[t];
    // --- QK^T (swapped), K fragments shared across both subtiles ---
#pragma unroll
    for (int ni = 0; ni < 4; ++ni) {
      const int r = ni * 16 + lr;
      bf16x8 k0 = lds128(Kb, r, lg);
      bf16x8 k1 = lds128(Kb, r, lg + 4);
      f32x4 zA = {0.f, 0.f, 0.f, 0.f};
      zA = MFMA_BF16(k0, qfA0, zA);
      zA = MFMA_BF16(k1, qfA1, zA);
      f32x4 zB = {0.f, 0.f, 0.f, 0.f};
      zB = MFMA_BF16(k0, qfB0, zB);
      zB = MFMA_BF16(k1, qfB1, zB);
      float pA[4], pB[4];
#pragma unroll
      for (int j = 0; j < 4; ++j) {
        const int bit = ni * 16 + lg * 4 + j;
        const float xA = ((mrA >> bit) & 1ull) ? mAltA : fmaf(zA[j], C2LOG2E, negllogA);
        const float xB = ((mrB >> bit) & 1ull) ? mAltB : fmaf(zB[j], C2LOG2E, negllogB);
        pA[j] = exp2_fast(xA);
        pB[j] = exp2_fast(xB);
      }
      ushort4 pkA = {rhu(pA[0]), rhu(pA[1]), rhu(pA[2]), rhu(pA[3])};
      ushort4 pkB = {rhu(pB[0]), rhu(pB[1]), rhu(pB[2]), rhu(pB[3])};
      *(ushort4*)&PwA[lr * PS + ni * 16 + lg * 4] = pkA;
      *(ushort4*)&PwB[lr * PS + ni * 16 + lg * 4] = pkB;
    }
    // --- PV: V fragments shared across both subtiles ---
    const bf16x8 pfA0 = *(const bf16x8*)&PwA[lr * PS + lg * 8];
    const bf16x8 pfA1 = *(const bf16x8*)&PwA[lr * PS + 32 + lg * 8];
    const bf16x8 pfB0 = *(const bf16x8*)&PwB[lr * PS + lg * 8];
    const bf16x8 pfB1 = *(const bf16x8*)&PwB[lr * PS + 32 + lg * 8];
#pragma unroll
    for (int nd = 0; nd < 4; ++nd) {
      const int r = nd * 16 + lr;
      bf16x8 v0 = lds128(Vb, r, lg);
      bf16x8 v1 = lds128(Vb, r, lg + 4);
      oA[nd] = MFMA_BF16(pfA0, v0, oA[nd]);
      oA[nd] = MFMA_BF16(pfA1, v1, oA[nd]);
      oB[nd] = MFMA_BF16(pfB0, v0, oB[nd]);
      oB[nd] = MFMA_BF16(pfB1, v1, oB[nd]);
    }
    // --- attn fp32 stores: verified pattern (row from lg, col from lr), NONTEMPORAL ---
#pragma unroll
    for (int j = 0; j < 4; ++j) {
      const int r = lg * 4 + j;
      ushort4 pkA = *(const ushort4*)&PwA[r * PS + lr * 4];
      f32x4 fA = {bf2f(pkA.x), bf2f(pkA.y), bf2f(pkA.z), bf2f(pkA.w)};
      __builtin_nontemporal_store(fA, (f32x4*)(ap + (size_t)(qbA + r) * SEQ + t * KT + lr * 4));
      ushort4 pkB = *(const ushort4*)&PwB[r * PS + lr * 4];
      f32x4 fB = {bf2f(pkB.x), bf2f(pkB.y), bf2f(pkB.z), bf2f(pkB.w)};
      __builtin_nontemporal_store(fB, (f32x4*)(ap + (size_t)(qbB + r) * SEQ + t * KT + lr * 4));
    }
    // --- counted-vmcnt barrier: wait the 4 gloads (t+1), leave the 8 newest stores in flight ---
    if (t + 1 < NT) {
      asm volatile("s_waitcnt vmcnt(8)" ::: "memory");
      __builtin_amdgcn_s_barrier();
    }
  }
  // ---- epilogue: write result in [b*S+s][h*64+d] bf16 layout, both subtiles ----
#pragma unroll
  for (int nd = 0; nd < 4; ++nd)
#pragma unroll
    for (int j = 0; j < 4; ++j) {
      R16[((size_t)(b * SEQ + qbA + lg * 4 + j)) * DM + (bh & 7) * DK + nd * 16 + lr] = f2bf(oA[nd][j]);
      R16[((size_t)(b * SEQ + qbB + lg * 4 + j)) * DM + (bh & 7) * DK + nd * 16 + lr] = f2bf(oB[nd][j]);
    }
}

// ---------- residual + LayerNorm (one wave per row) ----------
__global__ __launch_bounds__(256) void ln_kernel(const float* __restrict__ fc,
                                                 const float* __restrict__ xq,
                                                 const float* __restrict__ gamma,
                                                 const float* __restrict__ beta,
                                                 float* __restrict__ out) {
  const int row = blockIdx.x * 4 + (threadIdx.x >> 6);
  const int lane = threadIdx.x & 63;
  const float* f = fc + (size_t)row * DM;
  const float* x = xq + (size_t)row * DM;
  float v[8];
  float s = 0.f, ss = 0.f;
#pragma unroll
  for (int i = 0; i < 8; ++i) {
    const int c = lane + i * 64;
    const float t = f[c] + x[c];
    v[i] = t; s += t; ss += t * t;
  }
#pragma unroll
  for (int off = 1; off < 64; off <<= 1) {
    s  += __shfl_xor(s, off);
    ss += __shfl_xor(ss, off);
  }
  const float mu  = s * (1.f / 512.f);
  const float var = ss * (1.f / 512.f) - mu * mu;
  const float inv = rsqrtf(var + 1e-5f);
  float* op = out + (size_t)row * DM;
#pragma unroll
  for (int i = 0; i < 8; ++i) {
    const int c = lane + i * 64;
    op[c] = (v[i] - mu) * inv * gamma[c] + beta[c];
  }
}

// ---------- workspace layout (bytes) ----------
// phase A: XQ16 0, XK16 8388608, XV16 16777216, WQ16 25165824, WK16 25690112,
//          WV16 26214400, WF16 26738688, Qh 27262976, Kh 35651584, VT 44040192
// phase B (X dead): Mbits @0 (2MB), R16 @16777216 (8.4MB)
// phase C (Qh/Kh dead): FC32 @27262976 (16.7MB).

extern "C" void kernel_launch(void* const* d_in, const int* in_sizes, int n_in,
                              void* d_out, int out_size, void* d_ws, size_t ws_size,
                              hipStream_t stream) {
  const float* xq   = (const float*)d_in[0];
  const float* xk   = (const float*)d_in[1];
  const float* xv   = (const float*)d_in[2];
  const void*  mask = d_in[3];
  const float* wq   = (const float*)d_in[4];
  const float* wk   = (const float*)d_in[5];
  const float* wv   = (const float*)d_in[6];
  const float* wfc  = (const float*)d_in[7];
  const float* gamma = (const float*)d_in[8];
  const float* beta  = (const float*)d_in[9];

  float* out = (float*)d_out;
  float* attn_out = out + (size_t)BDIM * SEQ * DM;

  char* ws = (char*)d_ws;
  unsigned short* XQ16 = (unsigned short*)(ws);
  unsigned short* XK16 = (unsigned short*)(ws + 8388608);
  unsigned short* XV16 = (unsigned short*)(ws + 16777216);
  unsigned short* WQ16 = (unsigned short*)(ws + 25165824);
  unsigned short* WK16 = (unsigned short*)(ws + 25690112);
  unsigned short* WV16 = (unsigned short*)(ws + 26214400);
  unsigned short* WF16 = (unsigned short*)(ws + 26738688);
  unsigned short* Qh   = (unsigned short*)(ws + 27262976);
  unsigned short* Kh   = (unsigned short*)(ws + 35651584);
  unsigned short* VT   = (unsigned short*)(ws + 44040192);
  unsigned long long* Mbits = (unsigned long long*)(ws);        // reuse XQ16 (2MB)
  unsigned short* R16  = (unsigned short*)(ws + 16777216);      // reuse XV16
  float*          FC32 = (float*)(ws + 27262976);               // reuse Qh/Kh

  const int NX4 = BDIM * SEQ * DM / 4;   // 1,048,576
  const int NW4 = DM * DM / 4;           // 65,536

  cvt7_kernel<<<dim3(NX4 / 256, 7), 256, 0, stream>>>(xq, xk, xv, wq, wk, wv, wfc,
                                                      XQ16, XK16, XV16,
                                                      WQ16, WK16, WV16, WF16, NX4, NW4);
  proj_kernel<<<dim3(64, 4, 3), 256, 0, stream>>>(XQ16, XK16, XV16,
                                                  WQ16, WK16, WV16, Qh, Kh, VT);
  mask_pack_kernel<<<1024, 256, 0, stream>>>((const unsigned char*)mask,
                                             (const int*)mask, Mbits);
  attn_kernel<<<dim3(16, NH, BDIM), 256, 0, stream>>>(Qh, Kh, VT, Mbits, attn_out, R16);
  fc_kernel<<<dim3(64, 4, 1), 256, 0, stream>>>(R16, WF16, FC32);
  ln_kernel<<<2048, 256, 0, stream>>>(FC32, xq, gamma, beta, out);
}